// Round 3
// baseline (10855.972 us; speedup 1.0000x reference)
//
#include <hip/hip_runtime.h>
#include <math.h>

// ---------------- problem constants ----------------
#define NTOK 8192            // B*T
#define DM   512
#define HID  1024            // per-direction hidden
#define G3H  3072            // 3*HID
#define GOUT 2048            // 2*HID (bidir concat)
#define FFND 2048
#define NEXP 8

typedef float f32x4 __attribute__((ext_vector_type(4)));

// ---------------- ws layout (bytes) ----------------
#define XG_OFF    0ULL                 // fp32 [8192][6144] = 201326592
#define HG_OFF    0ULL                 // alias (after GRU): fp32 [16384][2048] = 134217728
#define OG_OFF    134217728ULL         // fp32 [16384][512] = 33554432 (inside xg region)
#define FLAT_OFF  201326592ULL         // fp32 [8192][2048] = 67108864
#define HBUF_OFF  268435456ULL         // fp32 [2 dir][2 parity][8192] = 131072 B
#define FLAGS_OFF 268566528ULL         // int flags[2][128]
#define IMETA_OFF 268567552ULL         // int meta, 4096
#define FMETA_OFF 268571648ULL         // float meta, 4096
#define TKIDX_OFF 268575744ULL         // int [16384]
#define TKW_OFF   268641280ULL         // float [16384]
#define PAIRT_OFF 268706816ULL         // int [16384]
#define PAIRW_OFF 268772352ULL         // float [16384]
#define SLOT_OFF  268837888ULL         // int [16384]
// imeta ints: [0..8) counts, [8..16) cursor, [16..25) offs, [25] Ttot,
//             [32..168) tileExp, [168..304) tileStart
// fmeta floats: [0..8) sumP, [8] zacc

// =====================================================================
// K0: zero hbuf + flags + meta (region [HBUF_OFF, TKIDX_OFF) = 35072 floats)
// =====================================================================
__global__ void k0_init(float* p) {
    int i = blockIdx.x * 256 + threadIdx.x;
    if (i < 35072) p[i] = 0.f;
}

// =====================================================================
// K1: fp32 SGEMM  C[M=8192][N=6144] = A[8192][512] * B[6144][512]^T + bias[N]
// =====================================================================
__global__ __launch_bounds__(256, 2) void k1_sgemm_bt(
    const float* __restrict__ A, const float* __restrict__ B,
    const float* __restrict__ bias, float* __restrict__ C) {
    __shared__ float As[16 * 132];
    __shared__ float Bs[16 * 132];
    const int tid = threadIdx.x;
    const int m0 = blockIdx.y * 128;
    const int n0 = blockIdx.x * 128;
    const int tx = tid & 15, ty = tid >> 4;
    const int arow = tid >> 2, ac4 = (tid & 3) * 4;
    float acc[8][8];
#pragma unroll
    for (int i = 0; i < 8; ++i)
#pragma unroll
        for (int j = 0; j < 8; ++j) acc[i][j] = 0.f;

    for (int k0 = 0; k0 < 512; k0 += 16) {
        __syncthreads();
#pragma unroll
        for (int r = 0; r < 2; ++r) {
            int row = r * 64 + arow;
            float4 va = *(const float4*)(A + (size_t)(m0 + row) * 512 + k0 + ac4);
            As[(ac4 + 0) * 132 + row] = va.x;
            As[(ac4 + 1) * 132 + row] = va.y;
            As[(ac4 + 2) * 132 + row] = va.z;
            As[(ac4 + 3) * 132 + row] = va.w;
            float4 vb = *(const float4*)(B + (size_t)(n0 + row) * 512 + k0 + ac4);
            Bs[(ac4 + 0) * 132 + row] = vb.x;
            Bs[(ac4 + 1) * 132 + row] = vb.y;
            Bs[(ac4 + 2) * 132 + row] = vb.z;
            Bs[(ac4 + 3) * 132 + row] = vb.w;
        }
        __syncthreads();
#pragma unroll
        for (int k = 0; k < 16; ++k) {
            float4 a0 = *(const float4*)&As[k * 132 + ty * 8];
            float4 a1 = *(const float4*)&As[k * 132 + ty * 8 + 4];
            float4 b0 = *(const float4*)&Bs[k * 132 + tx * 8];
            float4 b1 = *(const float4*)&Bs[k * 132 + tx * 8 + 4];
            float av[8] = {a0.x, a0.y, a0.z, a0.w, a1.x, a1.y, a1.z, a1.w};
            float bv[8] = {b0.x, b0.y, b0.z, b0.w, b1.x, b1.y, b1.z, b1.w};
#pragma unroll
            for (int i = 0; i < 8; ++i)
#pragma unroll
                for (int j = 0; j < 8; ++j) acc[i][j] = fmaf(av[i], bv[j], acc[i][j]);
        }
    }
    float4 c0 = *(const float4*)(bias + n0 + tx * 8);
    float4 c1 = *(const float4*)(bias + n0 + tx * 8 + 4);
    float bb[8] = {c0.x, c0.y, c0.z, c0.w, c1.x, c1.y, c1.z, c1.w};
#pragma unroll
    for (int i = 0; i < 8; ++i) {
        float* op = C + (size_t)(m0 + ty * 8 + i) * 6144 + n0 + tx * 8;
        float4 o0 = make_float4(acc[i][0] + bb[0], acc[i][1] + bb[1],
                                acc[i][2] + bb[2], acc[i][3] + bb[3]);
        float4 o1 = make_float4(acc[i][4] + bb[4], acc[i][5] + bb[5],
                                acc[i][6] + bb[6], acc[i][7] + bb[7]);
        *(float4*)op = o0;
        *(float4*)(op + 4) = o1;
    }
}

// =====================================================================
// K2: persistent bidirectional GRU, v4.
//  - Whh slice in VGPRs (96/thread, loaded once).
//  - Flag protocol (v1/v3, proven): producer stores h, waitcnt-drains,
//    posts flag; consumers wave-parallel poll 128 flags.
//  - NEW: bulk h stage uses 8x global_load_dwordx4 sc0 sc1 (L1+L2
//    bypass, coherent at LLC, request-coalesced) instead of 32 scalar
//    agent-atomic dword loads (which issue per-lane transactions).
//    LDS staging becomes 8x ds_write_b128.
// =====================================================================
__global__ __launch_bounds__(256) void k2_gru(
    const float* __restrict__ Whh, const float* __restrict__ bhh,
    const float* __restrict__ xg, float* __restrict__ flat,
    float* hbuf, int* flags) {
    __shared__ float hlsf[8192];        // swizzled h [1024][8], 32 KB
    __shared__ float red[64 * 196];     // partials [kc][24*8] pitch 196, 50 KB
    __shared__ float s2b[192];
    char* hls = (char*)hlsf;
    const int tid = threadIdx.x;
    const int dir = blockIdx.x >> 7;
    const int wg = blockIdx.x & 127;
    const int j0 = wg << 3;
    float* hb = hbuf + dir * 16384;
    int* fl = flags + dir * 128;
    const int rg = tid >> 6;            // 0..3
    const int kc = tid & 63;            // 0..63
    const int swz = (kc & 7) << 4;      // byte XOR for this thread's k-range
    const int lane = tid & 63;

    // ---- weights into registers: rows rg*6..+5, k = kc*16..+15 (one-time)
    const float* W0 = Whh + (size_t)dir * G3H * HID;
    float wreg[6][16];
#pragma unroll
    for (int rr = 0; rr < 6; ++rr) {
        const int r = rg * 6 + rr;
        const float* wp = W0 + (size_t)(((r >> 3) << 10) + j0 + (r & 7)) * 1024 + (kc << 4);
        const float4 w0 = ((const float4*)wp)[0];
        const float4 w1 = ((const float4*)wp)[1];
        const float4 w2 = ((const float4*)wp)[2];
        const float4 w3 = ((const float4*)wp)[3];
        wreg[rr][0] = w0.x;  wreg[rr][1] = w0.y;  wreg[rr][2] = w0.z;  wreg[rr][3] = w0.w;
        wreg[rr][4] = w1.x;  wreg[rr][5] = w1.y;  wreg[rr][6] = w1.z;  wreg[rr][7] = w1.w;
        wreg[rr][8] = w2.x;  wreg[rr][9] = w2.y;  wreg[rr][10] = w2.z; wreg[rr][11] = w2.w;
        wreg[rr][12] = w3.x; wreg[rr][13] = w3.y; wreg[rr][14] = w3.z; wreg[rr][15] = w3.w;
    }
    float bhh_r = 0.f;
    if (tid < 192) {
        const int r = tid >> 3;
        bhh_r = bhh[dir * G3H + ((r >> 3) << 10) + j0 + (r & 7)];
    }
    const int u = tid >> 3, bb = tid & 7;   // producer mapping (tid<64)
    const int wswz = ((tid >> 5) & 7) << 4; // staging-write XOR (constant/thread)
    float hprev = 0.f;

    for (int s = 1; s <= 1024; ++s) {
        const int te = dir ? (1024 - s) : (s - 1);
        // xg prefetch (latency hidden under poll+stage)
        float xr = 0.f, xz = 0.f, xn = 0.f;
        if (tid < 64) {
            const float* xp = xg + (size_t)((bb << 10) + te) * 6144 + dir * G3H + j0 + u;
            xr = xp[0];
            xz = xp[1024];
            xn = xp[2048];
        }
        // ---- wait for all 128 producers of step s-1 (wave-parallel poll)
        if (s > 1) {
            const int c0 = s - 1;
            int it = 0;
            for (;;) {
                int f0 = __hip_atomic_load(fl + lane, __ATOMIC_RELAXED, __HIP_MEMORY_SCOPE_AGENT);
                int f1 = __hip_atomic_load(fl + 64 + lane, __ATOMIC_RELAXED, __HIP_MEMORY_SCOPE_AGENT);
                if (__all((f0 >= c0) && (f1 >= c0))) break;
                if (++it > (1 << 22)) break;   // hang-guard only
                __builtin_amdgcn_s_sleep(1);
            }
        }
        // compiler barrier: keep the wide loads after the poll
        asm volatile("" ::: "memory");
        // ---- bulk-stage h(s-1): 8x dwordx4, L1+L2 bypass (coherent @ LLC),
        // properly request-coalesced (64 lanes x 16B contiguous per instr)
        const float* hp = hb + (((s - 1) & 1) << 13);
        const float* hbase = hp + (tid << 2);
        f32x4 hv4[8];
#pragma unroll
        for (int c = 0; c < 8; ++c)
            asm volatile("global_load_dwordx4 %0, %1, off sc0 sc1"
                         : "=v"(hv4[c]) : "v"(hbase + (c << 10)));
        asm volatile("s_waitcnt vmcnt(0)" ::: "memory");
        __builtin_amdgcn_sched_barrier(0);
        // ---- write h into swizzled LDS (b128, conflict-minimal)
#pragma unroll
        for (int c = 0; c < 8; ++c) {
            const int off = ((c << 12) + (tid << 4)) ^ wswz;
            *(f32x4*)(hls + off) = hv4[c];
        }
        __syncthreads();
        // ---- matvec: weights from regs, h fragments from swizzled LDS
        float acc[6][8];
#pragma unroll
        for (int rr = 0; rr < 6; ++rr)
#pragma unroll
            for (int q = 0; q < 8; ++q) acc[rr][q] = 0.f;
#pragma unroll
        for (int i = 0; i < 16; ++i) {
            const int kbase = ((kc << 4) + i) << 5;
            const float4 hA = *(const float4*)(hls + (kbase ^ swz));
            const float4 hB = *(const float4*)(hls + ((kbase + 16) ^ swz));
#pragma unroll
            for (int rr = 0; rr < 6; ++rr) {
                const float w = wreg[rr][i];
                acc[rr][0] = fmaf(w, hA.x, acc[rr][0]);
                acc[rr][1] = fmaf(w, hA.y, acc[rr][1]);
                acc[rr][2] = fmaf(w, hA.z, acc[rr][2]);
                acc[rr][3] = fmaf(w, hA.w, acc[rr][3]);
                acc[rr][4] = fmaf(w, hB.x, acc[rr][4]);
                acc[rr][5] = fmaf(w, hB.y, acc[rr][5]);
                acc[rr][6] = fmaf(w, hB.z, acc[rr][6]);
                acc[rr][7] = fmaf(w, hB.w, acc[rr][7]);
            }
        }
        // ---- partials to LDS
        float* rp = red + kc * 196 + rg * 48;
#pragma unroll
        for (int rr = 0; rr < 6; ++rr) {
            *(float4*)(rp + (rr << 3)) =
                make_float4(acc[rr][0], acc[rr][1], acc[rr][2], acc[rr][3]);
            *(float4*)(rp + (rr << 3) + 4) =
                make_float4(acc[rr][4], acc[rr][5], acc[rr][6], acc[rr][7]);
        }
        __syncthreads();
        if (tid < 192) {
            float a0 = 0.f, a1 = 0.f, a2 = 0.f, a3 = 0.f;
#pragma unroll
            for (int q = 0; q < 64; q += 4) {
                a0 += red[(q + 0) * 196 + tid];
                a1 += red[(q + 1) * 196 + tid];
                a2 += red[(q + 2) * 196 + tid];
                a3 += red[(q + 3) * 196 + tid];
            }
            s2b[tid] = (a0 + a1) + (a2 + a3) + bhh_r;
        }
        __syncthreads();
        if (tid < 64) {
            const float hr = s2b[tid];
            const float hz = s2b[64 + tid];
            const float hn = s2b[128 + tid];
            const float rg_ = 1.f / (1.f + expf(-(xr + hr)));
            const float zg_ = 1.f / (1.f + expf(-(xz + hz)));
            const float ng_ = tanhf(xn + rg_ * hn);
            const float hnew = (1.f - zg_) * ng_ + zg_ * hprev;
            hprev = hnew;
            // coherent h store first — the only thing consumers wait on
            __hip_atomic_store(hb + ((s & 1) << 13) + ((j0 + u) << 3) + bb, hnew,
                               __ATOMIC_RELAXED, __HIP_MEMORY_SCOPE_AGENT);
            // drain own stores, then post arrival flag
            __builtin_amdgcn_s_waitcnt(0);
            if (tid == 0)
                __hip_atomic_store(fl + wg, s, __ATOMIC_RELAXED, __HIP_MEMORY_SCOPE_AGENT);
            // flat store off the critical path (consumed only after kernel end)
            const float lr = hnew > 0.f ? hnew : 0.01f * hnew;
            flat[(size_t)((bb << 10) + te) * 2048 + dir * 1024 + j0 + u] = lr;
        }
    }
}

// =====================================================================
// K3: gating — fp32 logits from fp32 flat, softmax, top-2, aux partials
// =====================================================================
__global__ __launch_bounds__(256) void k3_gate(
    const float* __restrict__ flat, const float* __restrict__ gate_W,
    const float* __restrict__ gate_b,
    int* __restrict__ tk_idx, float* __restrict__ tk_w,
    int* __restrict__ counts, float* __restrict__ fmeta) {
    __shared__ float gw[8 * 2048];
    __shared__ float bP[9];
    __shared__ int bC[8];
    const int tid = threadIdx.x;
    for (int i = tid; i < 8 * 2048; i += 256) gw[i] = gate_W[i];
    if (tid < 9) bP[tid] = 0.f;
    if (tid < 8) bC[tid] = 0;
    __syncthreads();
    const int lane = tid & 63, w = tid >> 6;
    const int tbase = blockIdx.x * 16 + w * 4;
    for (int j = 0; j < 4; ++j) {
        int t = tbase + j;
        const float* fr = flat + (size_t)t * 2048;
        float a[8];
#pragma unroll
        for (int e = 0; e < 8; ++e) a[e] = 0.f;
        for (int i = 0; i < 32; ++i) {
            float v = fr[i * 64 + lane];
#pragma unroll
            for (int e = 0; e < 8; ++e) a[e] = fmaf(v, gw[e * 2048 + i * 64 + lane], a[e]);
        }
#pragma unroll
        for (int e = 0; e < 8; ++e) {
#pragma unroll
            for (int off = 32; off > 0; off >>= 1) a[e] += __shfl_down(a[e], off);
        }
        if (lane == 0) {
            float lg[8];
#pragma unroll
            for (int e = 0; e < 8; ++e) lg[e] = a[e] + gate_b[e];
            float m = lg[0];
#pragma unroll
            for (int e = 1; e < 8; ++e) m = fmaxf(m, lg[e]);
            float sc[8], ssum = 0.f;
#pragma unroll
            for (int e = 0; e < 8; ++e) { sc[e] = expf(lg[e] - m); ssum += sc[e]; }
            float inv = 1.f / ssum;
#pragma unroll
            for (int e = 0; e < 8; ++e) sc[e] *= inv;
            float lse = m + logf(ssum);
            int i1 = 0; float s1 = sc[0];
#pragma unroll
            for (int e = 1; e < 8; ++e) if (sc[e] > s1) { s1 = sc[e]; i1 = e; }
            int i2 = (i1 == 0) ? 1 : 0; float s2v = sc[i2];
#pragma unroll
            for (int e = 0; e < 8; ++e) if (e != i1 && sc[e] > s2v) { s2v = sc[e]; i2 = e; }
            float wsum = s1 + s2v;
            tk_idx[2 * t] = i1; tk_idx[2 * t + 1] = i2;
            tk_w[2 * t] = s1 / wsum; tk_w[2 * t + 1] = s2v / wsum;
            atomicAdd(&bC[i1], 1);
            atomicAdd(&bC[i2], 1);
#pragma unroll
            for (int e = 0; e < 8; ++e) atomicAdd(&bP[e], sc[e]);
            atomicAdd(&bP[8], lse * lse);
        }
    }
    __syncthreads();
    if (tid < 8) {
        atomicAdd(&counts[tid], bC[tid]);
        atomicAdd(&fmeta[tid], bP[tid]);
    }
    if (tid == 8) atomicAdd(&fmeta[8], bP[8]);
}

// =====================================================================
// K4: schedule (offsets, tile table) + aux loss
// =====================================================================
__global__ void k4_sched(int* im, float* fm, float* aux_out) {
    int tid = threadIdx.x;
    if (tid < 136) { im[32 + tid] = -1; im[168 + tid] = 0; }
    __syncthreads();
    if (tid == 0) {
        int off = 0;
        for (int e = 0; e < 8; ++e) { im[16 + e] = off; im[8 + e] = off; off += im[e]; }
        im[24] = off;
        int T = 0;
        for (int e = 0; e < 8; ++e) {
            int c = im[e], o = im[16 + e];
            for (int i = 0; i < c; i += 128) { im[32 + T] = e; im[168 + T] = o + i; ++T; }
        }
        im[25] = T;
        float fP = 0.f;
        for (int e = 0; e < 8; ++e) fP += ((float)im[e] / 8192.f) * (fm[e] / 8192.f);
        *aux_out = 0.01f * 8.f * fP + 0.001f * (fm[8] / 8192.f);
    }
}

// =====================================================================
// K5: scatter tokens into per-expert pair lists (block-aggregated atomics)
// =====================================================================
__global__ __launch_bounds__(256) void k5_scatter(
    const int* __restrict__ tk_idx, const float* __restrict__ tk_w,
    int* __restrict__ im, int* __restrict__ pair_t,
    float* __restrict__ pair_w, int* __restrict__ slot) {
    __shared__ int cnt[8], base[8];
    const int tid = threadIdx.x;
    if (tid < 8) cnt[tid] = 0;
    __syncthreads();
    const int t = blockIdx.x * 256 + tid;
    const int e0 = tk_idx[2 * t], e1 = tk_idx[2 * t + 1];
    const int p0 = atomicAdd(&cnt[e0], 1);
    const int p1 = atomicAdd(&cnt[e1], 1);
    __syncthreads();
    if (tid < 8) base[tid] = atomicAdd(&im[8 + tid], cnt[tid]);
    __syncthreads();
    const int q0 = base[e0] + p0, q1 = base[e1] + p1;
    pair_t[q0] = t; pair_w[q0] = tk_w[2 * t];     slot[2 * t] = q0;
    pair_t[q1] = t; pair_w[q1] = tk_w[2 * t + 1]; slot[2 * t + 1] = q1;
}

// =====================================================================
// K6: grouped FFN1 — Hg[p][f] = gelu(flat[token(p)] @ W1[e] + b1[e])
// =====================================================================
__global__ __launch_bounds__(256, 2) void k6_ffn1(
    const float* __restrict__ flat, const float* __restrict__ W1,
    const float* __restrict__ b1, const int* __restrict__ im,
    const int* __restrict__ pair_t, float* __restrict__ Hg) {
    const int rt = blockIdx.x % 136;
    const int nt = blockIdx.x / 136;
    const int e = im[32 + rt];
    if (e < 0) return;
    const int pStart = im[168 + rt];
    const int pEnd = im[16 + e + 1];
    __shared__ float As[16 * 132];
    __shared__ float Bs[16 * 132];
    const int tid = threadIdx.x;
    const int tx = tid & 15, ty = tid >> 4;
    const int n0 = nt * 128;
    const float* Bb = W1 + (size_t)e * 2048 * 2048;
    const int arow = tid >> 2, ac4 = (tid & 3) * 4;
    const int bk = tid >> 4, bn = (tid & 15) * 8;
    int r0 = pStart + arow;       if (r0 > pEnd - 1) r0 = pEnd - 1;
    int r1 = pStart + 64 + arow;  if (r1 > pEnd - 1) r1 = pEnd - 1;
    const float* arp0 = flat + (size_t)pair_t[r0] * 2048;
    const float* arp1 = flat + (size_t)pair_t[r1] * 2048;
    float acc[8][8];
#pragma unroll
    for (int i = 0; i < 8; ++i)
#pragma unroll
        for (int j = 0; j < 8; ++j) acc[i][j] = 0.f;

    for (int k0 = 0; k0 < 2048; k0 += 16) {
        __syncthreads();
        {
            float4 va = *(const float4*)(arp0 + k0 + ac4);
            As[(ac4 + 0) * 132 + arow] = va.x;
            As[(ac4 + 1) * 132 + arow] = va.y;
            As[(ac4 + 2) * 132 + arow] = va.z;
            As[(ac4 + 3) * 132 + arow] = va.w;
            float4 vb = *(const float4*)(arp1 + k0 + ac4);
            As[(ac4 + 0) * 132 + 64 + arow] = vb.x;
            As[(ac4 + 1) * 132 + 64 + arow] = vb.y;
            As[(ac4 + 2) * 132 + 64 + arow] = vb.z;
            As[(ac4 + 3) * 132 + 64 + arow] = vb.w;
            float4 w0 = *(const float4*)(Bb + (size_t)(k0 + bk) * 2048 + n0 + bn);
            float4 w1 = *(const float4*)(Bb + (size_t)(k0 + bk) * 2048 + n0 + bn + 4);
            *(float4*)&Bs[bk * 132 + bn] = w0;
            *(float4*)&Bs[bk * 132 + bn + 4] = w1;
        }
        __syncthreads();
#pragma unroll
        for (int k = 0; k < 16; ++k) {
            float4 a0 = *(const float4*)&As[k * 132 + ty * 8];
            float4 a1 = *(const float4*)&As[k * 132 + ty * 8 + 4];
            float4 b0 = *(const float4*)&Bs[k * 132 + tx * 8];
            float4 b1v = *(const float4*)&Bs[k * 132 + tx * 8 + 4];
            float av[8] = {a0.x, a0.y, a0.z, a0.w, a1.x, a1.y, a1.z, a1.w};
            float bv[8] = {b0.x, b0.y, b0.z, b0.w, b1v.x, b1v.y, b1v.z, b1v.w};
#pragma unroll
            for (int i = 0; i < 8; ++i)
#pragma unroll
                for (int j = 0; j < 8; ++j) acc[i][j] = fmaf(av[i], bv[j], acc[i][j]);
        }
    }
    float4 c0 = *(const float4*)(b1 + (size_t)e * 2048 + n0 + tx * 8);
    float4 c1 = *(const float4*)(b1 + (size_t)e * 2048 + n0 + tx * 8 + 4);
    float bb[8] = {c0.x, c0.y, c0.z, c0.w, c1.x, c1.y, c1.z, c1.w};
#pragma unroll
    for (int i = 0; i < 8; ++i) {
        int p = pStart + ty * 8 + i;
        if (p < pEnd) {
            float* op = Hg + (size_t)p * 2048 + n0 + tx * 8;
            float o[8];
#pragma unroll
            for (int j = 0; j < 8; ++j) {
                float xv = acc[i][j] + bb[j];
                o[j] = 0.5f * xv * (1.f + erff(xv * 0.70710678118654752f));
            }
            *(float4*)op = make_float4(o[0], o[1], o[2], o[3]);
            *(float4*)(op + 4) = make_float4(o[4], o[5], o[6], o[7]);
        }
    }
}

// =====================================================================
// K7: grouped FFN2 — Og[p][d] = Hg[p] @ W2[e] + b2[e]
// =====================================================================
__global__ __launch_bounds__(256, 2) void k7_ffn2(
    const float* __restrict__ Hg, const float* __restrict__ W2,
    const float* __restrict__ b2, const int* __restrict__ im,
    float* __restrict__ Og) {
    const int rt = blockIdx.x % 136;
    const int nt = blockIdx.x / 136;
    const int e = im[32 + rt];
    if (e < 0) return;
    const int pStart = im[168 + rt];
    const int pEnd = im[16 + e + 1];
    __shared__ float As[16 * 132];
    __shared__ float Bs[16 * 132];
    const int tid = threadIdx.x;
    const int tx = tid & 15, ty = tid >> 4;
    const int n0 = nt * 128;
    const float* Bb = W2 + (size_t)e * 2048 * 512;
    const int arow = tid >> 2, ac4 = (tid & 3) * 4;
    const int bk = tid >> 4, bn = (tid & 15) * 8;
    int r0 = pStart + arow;       if (r0 > pEnd - 1) r0 = pEnd - 1;
    int r1 = pStart + 64 + arow;  if (r1 > pEnd - 1) r1 = pEnd - 1;
    const float* arp0 = Hg + (size_t)r0 * 2048;
    const float* arp1 = Hg + (size_t)r1 * 2048;
    float acc[8][8];
#pragma unroll
    for (int i = 0; i < 8; ++i)
#pragma unroll
        for (int j = 0; j < 8; ++j) acc[i][j] = 0.f;

    for (int k0 = 0; k0 < 2048; k0 += 16) {
        __syncthreads();
        {
            float4 va = *(const float4*)(arp0 + k0 + ac4);
            As[(ac4 + 0) * 132 + arow] = va.x;
            As[(ac4 + 1) * 132 + arow] = va.y;
            As[(ac4 + 2) * 132 + arow] = va.z;
            As[(ac4 + 3) * 132 + arow] = va.w;
            float4 vb = *(const float4*)(arp1 + k0 + ac4);
            As[(ac4 + 0) * 132 + 64 + arow] = vb.x;
            As[(ac4 + 1) * 132 + 64 + arow] = vb.y;
            As[(ac4 + 2) * 132 + 64 + arow] = vb.z;
            As[(ac4 + 3) * 132 + 64 + arow] = vb.w;
            float4 w0 = *(const float4*)(Bb + (size_t)(k0 + bk) * 512 + n0 + bn);
            float4 w1 = *(const float4*)(Bb + (size_t)(k0 + bk) * 512 + n0 + bn + 4);
            *(float4*)&Bs[bk * 132 + bn] = w0;
            *(float4*)&Bs[bk * 132 + bn + 4] = w1;
        }
        __syncthreads();
#pragma unroll
        for (int k = 0; k < 16; ++k) {
            float4 a0 = *(const float4*)&As[k * 132 + ty * 8];
            float4 a1 = *(const float4*)&As[k * 132 + ty * 8 + 4];
            float4 b0 = *(const float4*)&Bs[k * 132 + tx * 8];
            float4 b1v = *(const float4*)&Bs[k * 132 + tx * 8 + 4];
            float av[8] = {a0.x, a0.y, a0.z, a0.w, a1.x, a1.y, a1.z, a1.w};
            float bv[8] = {b0.x, b0.y, b0.z, b0.w, b1v.x, b1v.y, b1v.z, b1v.w};
#pragma unroll
            for (int i = 0; i < 8; ++i)
#pragma unroll
                for (int j = 0; j < 8; ++j) acc[i][j] = fmaf(av[i], bv[j], acc[i][j]);
        }
    }
    float4 c0 = *(const float4*)(b2 + (size_t)e * 512 + n0 + tx * 8);
    float4 c1 = *(const float4*)(b2 + (size_t)e * 512 + n0 + tx * 8 + 4);
    float bb[8] = {c0.x, c0.y, c0.z, c0.w, c1.x, c1.y, c1.z, c1.w};
#pragma unroll
    for (int i = 0; i < 8; ++i) {
        int p = pStart + ty * 8 + i;
        if (p < pEnd) {
            float* op = Og + (size_t)p * 512 + n0 + tx * 8;
            *(float4*)op = make_float4(acc[i][0] + bb[0], acc[i][1] + bb[1],
                                       acc[i][2] + bb[2], acc[i][3] + bb[3]);
            *(float4*)(op + 4) = make_float4(acc[i][4] + bb[4], acc[i][5] + bb[5],
                                             acc[i][6] + bb[6], acc[i][7] + bb[7]);
        }
    }
}

// =====================================================================
// K8: combine — out[t] = w0*Og[s0] + w1*Og[s1]
// =====================================================================
__global__ __launch_bounds__(256) void k8_comb(
    const float* __restrict__ Og, const int* __restrict__ slot,
    const float* __restrict__ pw, float* __restrict__ out) {
    const int i4 = blockIdx.x * 256 + threadIdx.x;   // < 1048576
    const int t = i4 >> 7;
    const int d = (i4 & 127) << 2;
    const int s0 = slot[2 * t], s1 = slot[2 * t + 1];
    const float w0 = pw[s0], w1 = pw[s1];
    float4 a = *(const float4*)(Og + (size_t)s0 * 512 + d);
    float4 b = *(const float4*)(Og + (size_t)s1 * 512 + d);
    float4 o = make_float4(w0 * a.x + w1 * b.x, w0 * a.y + w1 * b.y,
                           w0 * a.z + w1 * b.z, w0 * a.w + w1 * b.w);
    *(float4*)(out + (size_t)t * 512 + d) = o;
}

// =====================================================================
extern "C" void kernel_launch(void* const* d_in, const int* in_sizes, int n_in,
                              void* d_out, int out_size, void* d_ws, size_t ws_size,
                              hipStream_t stream) {
    (void)in_sizes; (void)n_in; (void)out_size; (void)ws_size;
    const float* x   = (const float*)d_in[0];
    const float* Wih = (const float*)d_in[1];
    const float* Whh = (const float*)d_in[2];
    const float* bih = (const float*)d_in[3];
    const float* bhh = (const float*)d_in[4];
    const float* gW  = (const float*)d_in[5];
    const float* gb  = (const float*)d_in[6];
    const float* W1  = (const float*)d_in[7];
    const float* b1  = (const float*)d_in[8];
    const float* W2  = (const float*)d_in[9];
    const float* b2  = (const float*)d_in[10];
    float* out = (float*)d_out;
    char* ws = (char*)d_ws;
    float* xg    = (float*)(ws + XG_OFF);
    float* Hg    = (float*)(ws + HG_OFF);
    float* Og    = (float*)(ws + OG_OFF);
    float* flat  = (float*)(ws + FLAT_OFF);
    float* hbuf  = (float*)(ws + HBUF_OFF);
    int*   flags = (int*)(ws + FLAGS_OFF);
    int*   im    = (int*)(ws + IMETA_OFF);
    float* fm    = (float*)(ws + FMETA_OFF);
    int*   tki   = (int*)(ws + TKIDX_OFF);
    float* tkw   = (float*)(ws + TKW_OFF);
    int*   prt   = (int*)(ws + PAIRT_OFF);
    float* prw   = (float*)(ws + PAIRW_OFF);
    int*   slt   = (int*)(ws + SLOT_OFF);

    hipLaunchKernelGGL(k0_init, dim3(138), dim3(256), 0, stream, (float*)(ws + HBUF_OFF));
    hipLaunchKernelGGL(k1_sgemm_bt, dim3(48, 64), dim3(256), 0, stream, x, Wih, bih, xg);
    hipLaunchKernelGGL(k2_gru, dim3(256), dim3(256), 0, stream, Whh, bhh, xg, flat, hbuf, flags);
    hipLaunchKernelGGL(k3_gate, dim3(512), dim3(256), 0, stream, flat, gW, gb, tki, tkw, im, fm);
    hipLaunchKernelGGL(k4_sched, dim3(1), dim3(256), 0, stream, im, fm, out + 4194304);
    hipLaunchKernelGGL(k5_scatter, dim3(32), dim3(256), 0, stream, tki, tkw, im, prt, prw, slt);
    hipLaunchKernelGGL(k6_ffn1, dim3(136 * 16), dim3(256), 0, stream, flat, W1, b1, im, prt, Hg);
    hipLaunchKernelGGL(k7_ffn2, dim3(136 * 4), dim3(256), 0, stream, Hg, W2, b2, im, Og);
    hipLaunchKernelGGL(k8_comb, dim3(4096), dim3(256), 0, stream, Og, slt, prw, out);
}

// Round 4
// 9557.515 us; speedup vs baseline: 1.1359x; 1.1359x over previous
//
#include <hip/hip_runtime.h>
#include <math.h>

// ---------------- problem constants ----------------
#define NTOK 8192            // B*T
#define DM   512
#define HID  1024            // per-direction hidden
#define G3H  3072            // 3*HID
#define GOUT 2048            // 2*HID (bidir concat)
#define FFND 2048
#define NEXP 8

typedef float f32x4 __attribute__((ext_vector_type(4)));

// ---------------- ws layout (bytes) ----------------
#define XG_OFF    0ULL                 // fp32 [8192][6144] = 201326592
#define HG_OFF    0ULL                 // alias (after GRU): fp32 [16384][2048] = 134217728
#define OG_OFF    134217728ULL         // fp32 [16384][512] = 33554432 (inside xg region)
#define FLAT_OFF  201326592ULL         // fp32 [8192][2048] = 67108864
#define HBUF_OFF  268435456ULL         // fp32 [2 dir][2 parity][8192] = 131072 B (tagged)
#define FLAGS_OFF 268566528ULL         // (unused in v5)
#define IMETA_OFF 268567552ULL         // int meta, 4096
#define FMETA_OFF 268571648ULL         // float meta, 4096
#define TKIDX_OFF 268575744ULL         // int [16384]
#define TKW_OFF   268641280ULL         // float [16384]
#define PAIRT_OFF 268706816ULL         // int [16384]
#define PAIRW_OFF 268772352ULL         // float [16384]
#define SLOT_OFF  268837888ULL         // int [16384]
// imeta ints: [0..8) counts, [8..16) cursor, [16..25) offs, [25] Ttot,
//             [32..168) tileExp, [168..304) tileStart
// fmeta floats: [0..8) sumP, [8] zacc

// =====================================================================
// K0: init tagged hbuf (parity0 -> tag 0, parity1 -> tag 1 so zero-init
// cannot alias step-1 writes) + zero flags/meta region.
// =====================================================================
__global__ void k0_init(unsigned* p) {
    int i = blockIdx.x * 256 + threadIdx.x;
    if (i < 32768) p[i] = (unsigned)((i >> 13) & 1);   // hbuf [dir][parity][8192]
    else if (i < 35072) p[i] = 0u;                     // flags + meta
}

// =====================================================================
// K1: fp32 SGEMM  C[M=8192][N=6144] = A[8192][512] * B[6144][512]^T + bias[N]
// =====================================================================
__global__ __launch_bounds__(256, 2) void k1_sgemm_bt(
    const float* __restrict__ A, const float* __restrict__ B,
    const float* __restrict__ bias, float* __restrict__ C) {
    __shared__ float As[16 * 132];
    __shared__ float Bs[16 * 132];
    const int tid = threadIdx.x;
    const int m0 = blockIdx.y * 128;
    const int n0 = blockIdx.x * 128;
    const int tx = tid & 15, ty = tid >> 4;
    const int arow = tid >> 2, ac4 = (tid & 3) * 4;
    float acc[8][8];
#pragma unroll
    for (int i = 0; i < 8; ++i)
#pragma unroll
        for (int j = 0; j < 8; ++j) acc[i][j] = 0.f;

    for (int k0 = 0; k0 < 512; k0 += 16) {
        __syncthreads();
#pragma unroll
        for (int r = 0; r < 2; ++r) {
            int row = r * 64 + arow;
            float4 va = *(const float4*)(A + (size_t)(m0 + row) * 512 + k0 + ac4);
            As[(ac4 + 0) * 132 + row] = va.x;
            As[(ac4 + 1) * 132 + row] = va.y;
            As[(ac4 + 2) * 132 + row] = va.z;
            As[(ac4 + 3) * 132 + row] = va.w;
            float4 vb = *(const float4*)(B + (size_t)(n0 + row) * 512 + k0 + ac4);
            Bs[(ac4 + 0) * 132 + row] = vb.x;
            Bs[(ac4 + 1) * 132 + row] = vb.y;
            Bs[(ac4 + 2) * 132 + row] = vb.z;
            Bs[(ac4 + 3) * 132 + row] = vb.w;
        }
        __syncthreads();
#pragma unroll
        for (int k = 0; k < 16; ++k) {
            float4 a0 = *(const float4*)&As[k * 132 + ty * 8];
            float4 a1 = *(const float4*)&As[k * 132 + ty * 8 + 4];
            float4 b0 = *(const float4*)&Bs[k * 132 + tx * 8];
            float4 b1 = *(const float4*)&Bs[k * 132 + tx * 8 + 4];
            float av[8] = {a0.x, a0.y, a0.z, a0.w, a1.x, a1.y, a1.z, a1.w};
            float bv[8] = {b0.x, b0.y, b0.z, b0.w, b1.x, b1.y, b1.z, b1.w};
#pragma unroll
            for (int i = 0; i < 8; ++i)
#pragma unroll
                for (int j = 0; j < 8; ++j) acc[i][j] = fmaf(av[i], bv[j], acc[i][j]);
        }
    }
    float4 c0 = *(const float4*)(bias + n0 + tx * 8);
    float4 c1 = *(const float4*)(bias + n0 + tx * 8 + 4);
    float bb[8] = {c0.x, c0.y, c0.z, c0.w, c1.x, c1.y, c1.z, c1.w};
#pragma unroll
    for (int i = 0; i < 8; ++i) {
        float* op = C + (size_t)(m0 + ty * 8 + i) * 6144 + n0 + tx * 8;
        float4 o0 = make_float4(acc[i][0] + bb[0], acc[i][1] + bb[1],
                                acc[i][2] + bb[2], acc[i][3] + bb[3]);
        float4 o1 = make_float4(acc[i][4] + bb[4], acc[i][5] + bb[5],
                                acc[i][6] + bb[6], acc[i][7] + bb[7]);
        *(float4*)op = o0;
        *(float4*)(op + 4) = o1;
    }
}

// =====================================================================
// K2: persistent bidirectional GRU, v5.
//  - Whh slice in VGPRs (96/thread, loaded once).
//  - Exchange: tagged data (mantissa LSB = (s>>1)&1, parity = s&1).
//    Producer: tagged h store ONLY — no waitcnt drain, no flag.
//    Consumer: wave-parallel 128-element SAMPLE poll (1 elem/producer),
//    then bulk 8x dwordx4 sc0/sc1 load + verify ALL tags + bulk retry
//    (fixes v2's serial divergent retries).
// =====================================================================
__global__ __launch_bounds__(256) void k2_gru(
    const float* __restrict__ Whh, const float* __restrict__ bhh,
    const float* __restrict__ xg, float* __restrict__ flat,
    float* hbuf) {
    __shared__ float hlsf[8192];        // swizzled h [1024][8], 32 KB
    __shared__ float red[64 * 196];     // partials [kc][24*8] pitch 196, 50 KB
    __shared__ float s2b[192];
    char* hls = (char*)hlsf;
    const int tid = threadIdx.x;
    const int dir = blockIdx.x >> 7;
    const int wg = blockIdx.x & 127;
    const int j0 = wg << 3;
    float* hb = hbuf + dir * 16384;
    const int rg = tid >> 6;            // 0..3
    const int kc = tid & 63;            // 0..63
    const int swz = (kc & 7) << 4;      // byte XOR for this thread's k-range
    const int lane = tid & 63;

    // ---- weights into registers: rows rg*6..+5, k = kc*16..+15 (one-time)
    const float* W0 = Whh + (size_t)dir * G3H * HID;
    float wreg[6][16];
#pragma unroll
    for (int rr = 0; rr < 6; ++rr) {
        const int r = rg * 6 + rr;
        const float* wp = W0 + (size_t)(((r >> 3) << 10) + j0 + (r & 7)) * 1024 + (kc << 4);
        const float4 w0 = ((const float4*)wp)[0];
        const float4 w1 = ((const float4*)wp)[1];
        const float4 w2 = ((const float4*)wp)[2];
        const float4 w3 = ((const float4*)wp)[3];
        wreg[rr][0] = w0.x;  wreg[rr][1] = w0.y;  wreg[rr][2] = w0.z;  wreg[rr][3] = w0.w;
        wreg[rr][4] = w1.x;  wreg[rr][5] = w1.y;  wreg[rr][6] = w1.z;  wreg[rr][7] = w1.w;
        wreg[rr][8] = w2.x;  wreg[rr][9] = w2.y;  wreg[rr][10] = w2.z; wreg[rr][11] = w2.w;
        wreg[rr][12] = w3.x; wreg[rr][13] = w3.y; wreg[rr][14] = w3.z; wreg[rr][15] = w3.w;
    }
    float bhh_r = 0.f;
    if (tid < 192) {
        const int r = tid >> 3;
        bhh_r = bhh[dir * G3H + ((r >> 3) << 10) + j0 + (r & 7)];
    }
    const int u = tid >> 3, bb = tid & 7;   // producer mapping (tid<64)
    const int wswz = ((tid >> 5) & 7) << 4; // staging-write XOR (constant/thread)
    float hprev = 0.f;

    for (int s = 1; s <= 1024; ++s) {
        const int te = dir ? (1024 - s) : (s - 1);
        // xg prefetch (latency hidden under poll)
        float xr = 0.f, xz = 0.f, xn = 0.f;
        if (tid < 64) {
            const float* xp = xg + (size_t)((bb << 10) + te) * 6144 + dir * G3H + j0 + u;
            xr = xp[0];
            xz = xp[1024];
            xn = xp[2048];
        }
        const float* hp = hb + (((s - 1) & 1) << 13);
        const unsigned expb = (((unsigned)(s - 1)) >> 1) & 1u;
        // ---- sample poll: 1 element per producer WG (128 samples, wave-par)
        if (s > 1) {
            int it = 0;
            for (;;) {
                float a = __hip_atomic_load(hp + (lane << 6) + 17,
                                            __ATOMIC_RELAXED, __HIP_MEMORY_SCOPE_AGENT);
                float b = __hip_atomic_load(hp + 4096 + (lane << 6) + 17,
                                            __ATOMIC_RELAXED, __HIP_MEMORY_SCOPE_AGENT);
                bool ok = ((__float_as_uint(a) & 1u) == expb) &&
                          ((__float_as_uint(b) & 1u) == expb);
                if (__all(ok)) break;
                if (++it > (1 << 22)) break;   // hang-guard only
                __builtin_amdgcn_s_sleep(1);
            }
        }
        // ---- bulk-stage h(s-1): 8x dwordx4 sc0/sc1, verify ALL tags, bulk retry
        const float* hbase = hp + (tid << 2);
        f32x4 hv4[8];
        {
            int it2 = 0;
            for (;;) {
#pragma unroll
                for (int c = 0; c < 8; ++c)
                    asm volatile("global_load_dwordx4 %0, %1, off sc0 sc1"
                                 : "=v"(hv4[c]) : "v"(hbase + (c << 10)));
                asm volatile("s_waitcnt vmcnt(0)" ::: "memory");
                __builtin_amdgcn_sched_barrier(0);
                bool ok = true;
#pragma unroll
                for (int c = 0; c < 8; ++c) {
                    ok = ok && ((__float_as_uint(hv4[c].x) & 1u) == expb)
                            && ((__float_as_uint(hv4[c].y) & 1u) == expb)
                            && ((__float_as_uint(hv4[c].z) & 1u) == expb)
                            && ((__float_as_uint(hv4[c].w) & 1u) == expb);
                }
                if (__all(ok)) break;
                if (++it2 > (1 << 18)) break;  // hang-guard only
            }
        }
        // ---- write h into swizzled LDS (b128)
#pragma unroll
        for (int c = 0; c < 8; ++c) {
            const int off = ((c << 12) + (tid << 4)) ^ wswz;
            *(f32x4*)(hls + off) = hv4[c];
        }
        __syncthreads();
        // ---- matvec: weights from regs, h fragments from swizzled LDS
        float acc[6][8];
#pragma unroll
        for (int rr = 0; rr < 6; ++rr)
#pragma unroll
            for (int q = 0; q < 8; ++q) acc[rr][q] = 0.f;
#pragma unroll
        for (int i = 0; i < 16; ++i) {
            const int kbase = ((kc << 4) + i) << 5;
            const float4 hA = *(const float4*)(hls + (kbase ^ swz));
            const float4 hB = *(const float4*)(hls + ((kbase + 16) ^ swz));
#pragma unroll
            for (int rr = 0; rr < 6; ++rr) {
                const float w = wreg[rr][i];
                acc[rr][0] = fmaf(w, hA.x, acc[rr][0]);
                acc[rr][1] = fmaf(w, hA.y, acc[rr][1]);
                acc[rr][2] = fmaf(w, hA.z, acc[rr][2]);
                acc[rr][3] = fmaf(w, hA.w, acc[rr][3]);
                acc[rr][4] = fmaf(w, hB.x, acc[rr][4]);
                acc[rr][5] = fmaf(w, hB.y, acc[rr][5]);
                acc[rr][6] = fmaf(w, hB.z, acc[rr][6]);
                acc[rr][7] = fmaf(w, hB.w, acc[rr][7]);
            }
        }
        // ---- partials to LDS
        float* rp = red + kc * 196 + rg * 48;
#pragma unroll
        for (int rr = 0; rr < 6; ++rr) {
            *(float4*)(rp + (rr << 3)) =
                make_float4(acc[rr][0], acc[rr][1], acc[rr][2], acc[rr][3]);
            *(float4*)(rp + (rr << 3) + 4) =
                make_float4(acc[rr][4], acc[rr][5], acc[rr][6], acc[rr][7]);
        }
        __syncthreads();
        if (tid < 192) {
            float a0 = 0.f, a1 = 0.f, a2 = 0.f, a3 = 0.f;
#pragma unroll
            for (int q = 0; q < 64; q += 4) {
                a0 += red[(q + 0) * 196 + tid];
                a1 += red[(q + 1) * 196 + tid];
                a2 += red[(q + 2) * 196 + tid];
                a3 += red[(q + 3) * 196 + tid];
            }
            s2b[tid] = (a0 + a1) + (a2 + a3) + bhh_r;
        }
        __syncthreads();
        if (tid < 64) {
            const float hr = s2b[tid];
            const float hz = s2b[64 + tid];
            const float hn = s2b[128 + tid];
            const float rg_ = 1.f / (1.f + expf(-(xr + hr)));
            const float zg_ = 1.f / (1.f + expf(-(xz + hz)));
            const float ng_ = tanhf(xn + rg_ * hn);
            const float hnew = (1.f - zg_) * ng_ + zg_ * hprev;
            hprev = hnew;
            // tagged store — the data IS the signal (no drain, no flag)
            const unsigned hu = (__float_as_uint(hnew) & ~1u) | (((unsigned)s >> 1) & 1u);
            __hip_atomic_store(hb + ((s & 1) << 13) + ((j0 + u) << 3) + bb,
                               __uint_as_float(hu),
                               __ATOMIC_RELAXED, __HIP_MEMORY_SCOPE_AGENT);
            // flat store off the critical path (consumed only after kernel end)
            const float lr = hnew > 0.f ? hnew : 0.01f * hnew;
            flat[(size_t)((bb << 10) + te) * 2048 + dir * 1024 + j0 + u] = lr;
        }
    }
}

// =====================================================================
// K3: gating — fp32 logits from fp32 flat, softmax, top-2, aux partials
// =====================================================================
__global__ __launch_bounds__(256) void k3_gate(
    const float* __restrict__ flat, const float* __restrict__ gate_W,
    const float* __restrict__ gate_b,
    int* __restrict__ tk_idx, float* __restrict__ tk_w,
    int* __restrict__ counts, float* __restrict__ fmeta) {
    __shared__ float gw[8 * 2048];
    __shared__ float bP[9];
    __shared__ int bC[8];
    const int tid = threadIdx.x;
    for (int i = tid; i < 8 * 2048; i += 256) gw[i] = gate_W[i];
    if (tid < 9) bP[tid] = 0.f;
    if (tid < 8) bC[tid] = 0;
    __syncthreads();
    const int lane = tid & 63, w = tid >> 6;
    const int tbase = blockIdx.x * 16 + w * 4;
    for (int j = 0; j < 4; ++j) {
        int t = tbase + j;
        const float* fr = flat + (size_t)t * 2048;
        float a[8];
#pragma unroll
        for (int e = 0; e < 8; ++e) a[e] = 0.f;
        for (int i = 0; i < 32; ++i) {
            float v = fr[i * 64 + lane];
#pragma unroll
            for (int e = 0; e < 8; ++e) a[e] = fmaf(v, gw[e * 2048 + i * 64 + lane], a[e]);
        }
#pragma unroll
        for (int e = 0; e < 8; ++e) {
#pragma unroll
            for (int off = 32; off > 0; off >>= 1) a[e] += __shfl_down(a[e], off);
        }
        if (lane == 0) {
            float lg[8];
#pragma unroll
            for (int e = 0; e < 8; ++e) lg[e] = a[e] + gate_b[e];
            float m = lg[0];
#pragma unroll
            for (int e = 1; e < 8; ++e) m = fmaxf(m, lg[e]);
            float sc[8], ssum = 0.f;
#pragma unroll
            for (int e = 0; e < 8; ++e) { sc[e] = expf(lg[e] - m); ssum += sc[e]; }
            float inv = 1.f / ssum;
#pragma unroll
            for (int e = 0; e < 8; ++e) sc[e] *= inv;
            float lse = m + logf(ssum);
            int i1 = 0; float s1 = sc[0];
#pragma unroll
            for (int e = 1; e < 8; ++e) if (sc[e] > s1) { s1 = sc[e]; i1 = e; }
            int i2 = (i1 == 0) ? 1 : 0; float s2v = sc[i2];
#pragma unroll
            for (int e = 0; e < 8; ++e) if (e != i1 && sc[e] > s2v) { s2v = sc[e]; i2 = e; }
            float wsum = s1 + s2v;
            tk_idx[2 * t] = i1; tk_idx[2 * t + 1] = i2;
            tk_w[2 * t] = s1 / wsum; tk_w[2 * t + 1] = s2v / wsum;
            atomicAdd(&bC[i1], 1);
            atomicAdd(&bC[i2], 1);
#pragma unroll
            for (int e = 0; e < 8; ++e) atomicAdd(&bP[e], sc[e]);
            atomicAdd(&bP[8], lse * lse);
        }
    }
    __syncthreads();
    if (tid < 8) {
        atomicAdd(&counts[tid], bC[tid]);
        atomicAdd(&fmeta[tid], bP[tid]);
    }
    if (tid == 8) atomicAdd(&fmeta[8], bP[8]);
}

// =====================================================================
// K4: schedule (offsets, tile table) + aux loss
// =====================================================================
__global__ void k4_sched(int* im, float* fm, float* aux_out) {
    int tid = threadIdx.x;
    if (tid < 136) { im[32 + tid] = -1; im[168 + tid] = 0; }
    __syncthreads();
    if (tid == 0) {
        int off = 0;
        for (int e = 0; e < 8; ++e) { im[16 + e] = off; im[8 + e] = off; off += im[e]; }
        im[24] = off;
        int T = 0;
        for (int e = 0; e < 8; ++e) {
            int c = im[e], o = im[16 + e];
            for (int i = 0; i < c; i += 128) { im[32 + T] = e; im[168 + T] = o + i; ++T; }
        }
        im[25] = T;
        float fP = 0.f;
        for (int e = 0; e < 8; ++e) fP += ((float)im[e] / 8192.f) * (fm[e] / 8192.f);
        *aux_out = 0.01f * 8.f * fP + 0.001f * (fm[8] / 8192.f);
    }
}

// =====================================================================
// K5: scatter tokens into per-expert pair lists (block-aggregated atomics)
// =====================================================================
__global__ __launch_bounds__(256) void k5_scatter(
    const int* __restrict__ tk_idx, const float* __restrict__ tk_w,
    int* __restrict__ im, int* __restrict__ pair_t,
    float* __restrict__ pair_w, int* __restrict__ slot) {
    __shared__ int cnt[8], base[8];
    const int tid = threadIdx.x;
    if (tid < 8) cnt[tid] = 0;
    __syncthreads();
    const int t = blockIdx.x * 256 + tid;
    const int e0 = tk_idx[2 * t], e1 = tk_idx[2 * t + 1];
    const int p0 = atomicAdd(&cnt[e0], 1);
    const int p1 = atomicAdd(&cnt[e1], 1);
    __syncthreads();
    if (tid < 8) base[tid] = atomicAdd(&im[8 + tid], cnt[tid]);
    __syncthreads();
    const int q0 = base[e0] + p0, q1 = base[e1] + p1;
    pair_t[q0] = t; pair_w[q0] = tk_w[2 * t];     slot[2 * t] = q0;
    pair_t[q1] = t; pair_w[q1] = tk_w[2 * t + 1]; slot[2 * t + 1] = q1;
}

// =====================================================================
// K6: grouped FFN1 — Hg[p][f] = gelu(flat[token(p)] @ W1[e] + b1[e])
// =====================================================================
__global__ __launch_bounds__(256, 2) void k6_ffn1(
    const float* __restrict__ flat, const float* __restrict__ W1,
    const float* __restrict__ b1, const int* __restrict__ im,
    const int* __restrict__ pair_t, float* __restrict__ Hg) {
    const int rt = blockIdx.x % 136;
    const int nt = blockIdx.x / 136;
    const int e = im[32 + rt];
    if (e < 0) return;
    const int pStart = im[168 + rt];
    const int pEnd = im[16 + e + 1];
    __shared__ float As[16 * 132];
    __shared__ float Bs[16 * 132];
    const int tid = threadIdx.x;
    const int tx = tid & 15, ty = tid >> 4;
    const int n0 = nt * 128;
    const float* Bb = W1 + (size_t)e * 2048 * 2048;
    const int arow = tid >> 2, ac4 = (tid & 3) * 4;
    const int bk = tid >> 4, bn = (tid & 15) * 8;
    int r0 = pStart + arow;       if (r0 > pEnd - 1) r0 = pEnd - 1;
    int r1 = pStart + 64 + arow;  if (r1 > pEnd - 1) r1 = pEnd - 1;
    const float* arp0 = flat + (size_t)pair_t[r0] * 2048;
    const float* arp1 = flat + (size_t)pair_t[r1] * 2048;
    float acc[8][8];
#pragma unroll
    for (int i = 0; i < 8; ++i)
#pragma unroll
        for (int j = 0; j < 8; ++j) acc[i][j] = 0.f;

    for (int k0 = 0; k0 < 2048; k0 += 16) {
        __syncthreads();
        {
            float4 va = *(const float4*)(arp0 + k0 + ac4);
            As[(ac4 + 0) * 132 + arow] = va.x;
            As[(ac4 + 1) * 132 + arow] = va.y;
            As[(ac4 + 2) * 132 + arow] = va.z;
            As[(ac4 + 3) * 132 + arow] = va.w;
            float4 vb = *(const float4*)(arp1 + k0 + ac4);
            As[(ac4 + 0) * 132 + 64 + arow] = vb.x;
            As[(ac4 + 1) * 132 + 64 + arow] = vb.y;
            As[(ac4 + 2) * 132 + 64 + arow] = vb.z;
            As[(ac4 + 3) * 132 + 64 + arow] = vb.w;
            float4 w0 = *(const float4*)(Bb + (size_t)(k0 + bk) * 2048 + n0 + bn);
            float4 w1 = *(const float4*)(Bb + (size_t)(k0 + bk) * 2048 + n0 + bn + 4);
            *(float4*)&Bs[bk * 132 + bn] = w0;
            *(float4*)&Bs[bk * 132 + bn + 4] = w1;
        }
        __syncthreads();
#pragma unroll
        for (int k = 0; k < 16; ++k) {
            float4 a0 = *(const float4*)&As[k * 132 + ty * 8];
            float4 a1 = *(const float4*)&As[k * 132 + ty * 8 + 4];
            float4 b0 = *(const float4*)&Bs[k * 132 + tx * 8];
            float4 b1v = *(const float4*)&Bs[k * 132 + tx * 8 + 4];
            float av[8] = {a0.x, a0.y, a0.z, a0.w, a1.x, a1.y, a1.z, a1.w};
            float bv[8] = {b0.x, b0.y, b0.z, b0.w, b1v.x, b1v.y, b1v.z, b1v.w};
#pragma unroll
            for (int i = 0; i < 8; ++i)
#pragma unroll
                for (int j = 0; j < 8; ++j) acc[i][j] = fmaf(av[i], bv[j], acc[i][j]);
        }
    }
    float4 c0 = *(const float4*)(b1 + (size_t)e * 2048 + n0 + tx * 8);
    float4 c1 = *(const float4*)(b1 + (size_t)e * 2048 + n0 + tx * 8 + 4);
    float bb[8] = {c0.x, c0.y, c0.z, c0.w, c1.x, c1.y, c1.z, c1.w};
#pragma unroll
    for (int i = 0; i < 8; ++i) {
        int p = pStart + ty * 8 + i;
        if (p < pEnd) {
            float* op = Hg + (size_t)p * 2048 + n0 + tx * 8;
            float o[8];
#pragma unroll
            for (int j = 0; j < 8; ++j) {
                float xv = acc[i][j] + bb[j];
                o[j] = 0.5f * xv * (1.f + erff(xv * 0.70710678118654752f));
            }
            *(float4*)op = make_float4(o[0], o[1], o[2], o[3]);
            *(float4*)(op + 4) = make_float4(o[4], o[5], o[6], o[7]);
        }
    }
}

// =====================================================================
// K7: grouped FFN2 — Og[p][d] = Hg[p] @ W2[e] + b2[e]
// =====================================================================
__global__ __launch_bounds__(256, 2) void k7_ffn2(
    const float* __restrict__ Hg, const float* __restrict__ W2,
    const float* __restrict__ b2, const int* __restrict__ im,
    float* __restrict__ Og) {
    const int rt = blockIdx.x % 136;
    const int nt = blockIdx.x / 136;
    const int e = im[32 + rt];
    if (e < 0) return;
    const int pStart = im[168 + rt];
    const int pEnd = im[16 + e + 1];
    __shared__ float As[16 * 132];
    __shared__ float Bs[16 * 132];
    const int tid = threadIdx.x;
    const int tx = tid & 15, ty = tid >> 4;
    const int n0 = nt * 128;
    const float* Bb = W2 + (size_t)e * 2048 * 512;
    const int arow = tid >> 2, ac4 = (tid & 3) * 4;
    const int bk = tid >> 4, bn = (tid & 15) * 8;
    int r0 = pStart + arow;       if (r0 > pEnd - 1) r0 = pEnd - 1;
    int r1 = pStart + 64 + arow;  if (r1 > pEnd - 1) r1 = pEnd - 1;
    const float* arp0 = Hg + (size_t)r0 * 2048;
    const float* arp1 = Hg + (size_t)r1 * 2048;
    float acc[8][8];
#pragma unroll
    for (int i = 0; i < 8; ++i)
#pragma unroll
        for (int j = 0; j < 8; ++j) acc[i][j] = 0.f;

    for (int k0 = 0; k0 < 2048; k0 += 16) {
        __syncthreads();
        {
            float4 va = *(const float4*)(arp0 + k0 + ac4);
            As[(ac4 + 0) * 132 + arow] = va.x;
            As[(ac4 + 1) * 132 + arow] = va.y;
            As[(ac4 + 2) * 132 + arow] = va.z;
            As[(ac4 + 3) * 132 + arow] = va.w;
            float4 vb = *(const float4*)(arp1 + k0 + ac4);
            As[(ac4 + 0) * 132 + 64 + arow] = vb.x;
            As[(ac4 + 1) * 132 + 64 + arow] = vb.y;
            As[(ac4 + 2) * 132 + 64 + arow] = vb.z;
            As[(ac4 + 3) * 132 + 64 + arow] = vb.w;
            float4 w0 = *(const float4*)(Bb + (size_t)(k0 + bk) * 512 + n0 + bn);
            float4 w1 = *(const float4*)(Bb + (size_t)(k0 + bk) * 512 + n0 + bn + 4);
            *(float4*)&Bs[bk * 132 + bn] = w0;
            *(float4*)&Bs[bk * 132 + bn + 4] = w1;
        }
        __syncthreads();
#pragma unroll
        for (int k = 0; k < 16; ++k) {
            float4 a0 = *(const float4*)&As[k * 132 + ty * 8];
            float4 a1 = *(const float4*)&As[k * 132 + ty * 8 + 4];
            float4 b0 = *(const float4*)&Bs[k * 132 + tx * 8];
            float4 b1v = *(const float4*)&Bs[k * 132 + tx * 8 + 4];
            float av[8] = {a0.x, a0.y, a0.z, a0.w, a1.x, a1.y, a1.z, a1.w};
            float bv[8] = {b0.x, b0.y, b0.z, b0.w, b1v.x, b1v.y, b1v.z, b1v.w};
#pragma unroll
            for (int i = 0; i < 8; ++i)
#pragma unroll
                for (int j = 0; j < 8; ++j) acc[i][j] = fmaf(av[i], bv[j], acc[i][j]);
        }
    }
    float4 c0 = *(const float4*)(b2 + (size_t)e * 512 + n0 + tx * 8);
    float4 c1 = *(const float4*)(b2 + (size_t)e * 512 + n0 + tx * 8 + 4);
    float bb[8] = {c0.x, c0.y, c0.z, c0.w, c1.x, c1.y, c1.z, c1.w};
#pragma unroll
    for (int i = 0; i < 8; ++i) {
        int p = pStart + ty * 8 + i;
        if (p < pEnd) {
            float* op = Og + (size_t)p * 512 + n0 + tx * 8;
            *(float4*)op = make_float4(acc[i][0] + bb[0], acc[i][1] + bb[1],
                                       acc[i][2] + bb[2], acc[i][3] + bb[3]);
            *(float4*)(op + 4) = make_float4(acc[i][4] + bb[4], acc[i][5] + bb[5],
                                             acc[i][6] + bb[6], acc[i][7] + bb[7]);
        }
    }
}

// =====================================================================
// K8: combine — out[t] = w0*Og[s0] + w1*Og[s1]
// =====================================================================
__global__ __launch_bounds__(256) void k8_comb(
    const float* __restrict__ Og, const int* __restrict__ slot,
    const float* __restrict__ pw, float* __restrict__ out) {
    const int i4 = blockIdx.x * 256 + threadIdx.x;   // < 1048576
    const int t = i4 >> 7;
    const int d = (i4 & 127) << 2;
    const int s0 = slot[2 * t], s1 = slot[2 * t + 1];
    const float w0 = pw[s0], w1 = pw[s1];
    float4 a = *(const float4*)(Og + (size_t)s0 * 512 + d);
    float4 b = *(const float4*)(Og + (size_t)s1 * 512 + d);
    float4 o = make_float4(w0 * a.x + w1 * b.x, w0 * a.y + w1 * b.y,
                           w0 * a.z + w1 * b.z, w0 * a.w + w1 * b.w);
    *(float4*)(out + (size_t)t * 512 + d) = o;
}

// =====================================================================
extern "C" void kernel_launch(void* const* d_in, const int* in_sizes, int n_in,
                              void* d_out, int out_size, void* d_ws, size_t ws_size,
                              hipStream_t stream) {
    (void)in_sizes; (void)n_in; (void)out_size; (void)ws_size;
    const float* x   = (const float*)d_in[0];
    const float* Wih = (const float*)d_in[1];
    const float* Whh = (const float*)d_in[2];
    const float* bih = (const float*)d_in[3];
    const float* bhh = (const float*)d_in[4];
    const float* gW  = (const float*)d_in[5];
    const float* gb  = (const float*)d_in[6];
    const float* W1  = (const float*)d_in[7];
    const float* b1  = (const float*)d_in[8];
    const float* W2  = (const float*)d_in[9];
    const float* b2  = (const float*)d_in[10];
    float* out = (float*)d_out;
    char* ws = (char*)d_ws;
    float* xg    = (float*)(ws + XG_OFF);
    float* Hg    = (float*)(ws + HG_OFF);
    float* Og    = (float*)(ws + OG_OFF);
    float* flat  = (float*)(ws + FLAT_OFF);
    float* hbuf  = (float*)(ws + HBUF_OFF);
    int*   im    = (int*)(ws + IMETA_OFF);
    float* fm    = (float*)(ws + FMETA_OFF);
    int*   tki   = (int*)(ws + TKIDX_OFF);
    float* tkw   = (float*)(ws + TKW_OFF);
    int*   prt   = (int*)(ws + PAIRT_OFF);
    float* prw   = (float*)(ws + PAIRW_OFF);
    int*   slt   = (int*)(ws + SLOT_OFF);

    hipLaunchKernelGGL(k0_init, dim3(138), dim3(256), 0, stream, (unsigned*)(ws + HBUF_OFF));
    hipLaunchKernelGGL(k1_sgemm_bt, dim3(48, 64), dim3(256), 0, stream, x, Wih, bih, xg);
    hipLaunchKernelGGL(k2_gru, dim3(256), dim3(256), 0, stream, Whh, bhh, xg, flat, hbuf);
    hipLaunchKernelGGL(k3_gate, dim3(512), dim3(256), 0, stream, flat, gW, gb, tki, tkw, im, fm);
    hipLaunchKernelGGL(k4_sched, dim3(1), dim3(256), 0, stream, im, fm, out + 4194304);
    hipLaunchKernelGGL(k5_scatter, dim3(32), dim3(256), 0, stream, tki, tkw, im, prt, prw, slt);
    hipLaunchKernelGGL(k6_ffn1, dim3(136 * 16), dim3(256), 0, stream, flat, W1, b1, im, prt, Hg);
    hipLaunchKernelGGL(k7_ffn2, dim3(136 * 4), dim3(256), 0, stream, Hg, W2, b2, im, Og);
    hipLaunchKernelGGL(k8_comb, dim3(4096), dim3(256), 0, stream, Og, slt, prw, out);
}